// Round 3
// baseline (147.057 us; speedup 1.0000x reference)
//
#include <hip/hip_runtime.h>

// out = 2 * heatmap_loss (offset term cancels: o / stopgrad(o/h) == h).
// heatmap_loss = sum_all(w * huber(pred,gt)) / 16  ->  out = sum/8.

typedef float v4f __attribute__((ext_vector_type(4)));

// Compiler defeated 3 attempts at keeping 8 loads in flight (VGPR 36->24->20,
// it serializes the batch under its pressure heuristic). Force it: volatile
// inline-asm loads cannot be reordered/collapsed, dest VGPRs stay live, and
// SIInsertWaitcnts doesn't track them -- we drain with ONE counted waitcnt.
__device__ __forceinline__ v4f gl4(const v4f* addr) {
    v4f r;
    asm volatile("global_load_dwordx4 %0, %1, off" : "=v"(r) : "v"(addr));
    return r;
}

__device__ __forceinline__ float hterm(float p, float g) {
    float err  = fabsf(p - g);
    float quad = fminf(err, 1.0f);      // clip(err, 0, delta=1)
    float lin  = err - quad;
    float h    = 0.5f * quad * quad + lin;
    float w    = (g != 0.0f) ? 1.5f : 0.6f;
    return w * h;
}

__device__ __forceinline__ float hterm4(v4f p, v4f g) {
    return hterm(p[0], g[0]) + hterm(p[1], g[1])
         + hterm(p[2], g[2]) + hterm(p[3], g[3]);
}

#define PAIRS 4

__global__ __launch_bounds__(256, 8) void heatmap_reduce_kernel(
        const v4f* __restrict__ pred,
        const v4f* __restrict__ gt,
        float* __restrict__ partial, int stride) {
    const int tid = blockIdx.x * 256 + threadIdx.x;

    v4f p[PAIRS], g[PAIRS];

    // 8 global_load_dwordx4 issued back-to-back, all in flight.
    #pragma unroll
    for (int j = 0; j < PAIRS; ++j) p[j] = gl4(pred + tid + j * stride);
    #pragma unroll
    for (int j = 0; j < PAIRS; ++j) g[j] = gl4(gt + tid + j * stride);

    // Manual drain. sched_barrier is MANDATORY: "memory" does not order the
    // register-only consumers below against the waitcnt (guide rule #18).
    asm volatile("s_waitcnt vmcnt(0)" ::: "memory");
    __builtin_amdgcn_sched_barrier(0);

    float acc = 0.0f;
    #pragma unroll
    for (int j = 0; j < PAIRS; ++j)
        acc += hterm4(p[j], g[j]);

    #pragma unroll
    for (int off = 32; off > 0; off >>= 1)
        acc += __shfl_down(acc, off, 64);

    __shared__ float wsum[4];
    int lane = threadIdx.x & 63;
    int wave = threadIdx.x >> 6;
    if (lane == 0) wsum[wave] = acc;
    __syncthreads();

    if (threadIdx.x == 0)
        partial[blockIdx.x] = wsum[0] + wsum[1] + wsum[2] + wsum[3];
}

__global__ __launch_bounds__(256) void finalize_kernel(
        const float4* __restrict__ partial4, float* __restrict__ out, int nblocks4) {
    float s = 0.0f;
    for (int i = threadIdx.x; i < nblocks4; i += 256) {
        float4 v = partial4[i];
        s += (v.x + v.y) + (v.z + v.w);
    }

    #pragma unroll
    for (int off = 32; off > 0; off >>= 1)
        s += __shfl_down(s, off, 64);

    __shared__ float wsum[4];
    int lane = threadIdx.x & 63;
    int wave = threadIdx.x >> 6;
    if (lane == 0) wsum[wave] = s;
    __syncthreads();

    if (threadIdx.x == 0)
        out[0] = (wsum[0] + wsum[1] + wsum[2] + wsum[3]) * 0.125f;
}

extern "C" void kernel_launch(void* const* d_in, const int* in_sizes, int n_in,
                              void* d_out, int out_size, void* d_ws, size_t ws_size,
                              hipStream_t stream) {
    const float* pred = (const float*)d_in[0];
    const float* gt   = (const float*)d_in[1];
    float* out     = (float*)d_out;
    float* partial = (float*)d_ws;

    int n  = in_sizes[0];        // 2*8*64*128*128 = 16,777,216
    int n4 = n >> 2;             // 4,194,304 float4s

    const int block  = 256;
    const int grid   = n4 / (block * PAIRS);   // 4096 blocks: 16/CU, 2 rounds of 8
    const int stride = grid * block;           // float4 stride between j-steps

    heatmap_reduce_kernel<<<grid, block, 0, stream>>>(
        (const v4f*)pred, (const v4f*)gt, partial, stride);

    finalize_kernel<<<1, block, 0, stream>>>(
        (const float4*)partial, out, grid / 4);
}

// Round 4
// 141.904 us; speedup vs baseline: 1.0363x; 1.0363x over previous
//
#include <hip/hip_runtime.h>

// out = 2 * heatmap_loss (offset term cancels: o / stopgrad(o/h) == h).
// heatmap_loss = sum_all(w * huber(pred,gt)) / 16  ->  out = sum/8.

typedef float v4f __attribute__((ext_vector_type(4)));

// asm-volatile load: compiler cannot reorder/collapse it, does not track its
// vmcnt -- WE manage drains with counted s_waitcnt (AITER/T4 pattern).
__device__ __forceinline__ v4f gl4(const v4f* addr) {
    v4f r;
    asm volatile("global_load_dwordx4 %0, %1, off" : "=v"(r) : "v"(addr));
    return r;
}

__device__ __forceinline__ float hterm(float p, float g) {
    float err  = fabsf(p - g);
    float quad = fminf(err, 1.0f);      // clip(err, 0, delta=1)
    float lin  = err - quad;
    float h    = 0.5f * quad * quad + lin;
    float w    = (g != 0.0f) ? 1.5f : 0.6f;
    return w * h;
}

__device__ __forceinline__ float hterm4(v4f p, v4f g) {
    return hterm(p[0], g[0]) + hterm(p[1], g[1])
         + hterm(p[2], g[2]) + hterm(p[3], g[3]);
}

#define BATCH 4    // float4-pairs per batch -> 8 loads = 8KB/wave per batch
#define NBATCH 4   // 16 pairs/thread total; grid = n4/(256*16) = 1024 persistent

// Counted-vmcnt software pipeline, 2 register buffers (X,Y), steady state
// 16 outstanding dwordx4 per wave (16KB), never draining to 0 mid-loop.
__global__ __launch_bounds__(256) void heatmap_reduce_kernel(
        const v4f* __restrict__ pred,
        const v4f* __restrict__ gt,
        float* __restrict__ partial, int stride) {
    const int tid = blockIdx.x * 256 + threadIdx.x;

    v4f px[BATCH], pgx[BATCH];   // buffer X
    v4f py[BATCH], pgy[BATCH];   // buffer Y

    // issue A -> X, B -> Y : 16 loads in flight
    #pragma unroll
    for (int j = 0; j < BATCH; ++j) {
        px[j]  = gl4(pred + tid + (0 * BATCH + j) * stride);
        pgx[j] = gl4(gt   + tid + (0 * BATCH + j) * stride);
    }
    #pragma unroll
    for (int j = 0; j < BATCH; ++j) {
        py[j]  = gl4(pred + tid + (1 * BATCH + j) * stride);
        pgy[j] = gl4(gt   + tid + (1 * BATCH + j) * stride);
    }

    float acc = 0.0f;

    // phase 1: A landed -> consume X, refill X with C (B still in flight)
    asm volatile("s_waitcnt vmcnt(8)");
    __builtin_amdgcn_sched_barrier(0);
    #pragma unroll
    for (int j = 0; j < BATCH; ++j) acc += hterm4(px[j], pgx[j]);
    #pragma unroll
    for (int j = 0; j < BATCH; ++j) {
        px[j]  = gl4(pred + tid + (2 * BATCH + j) * stride);
        pgx[j] = gl4(gt   + tid + (2 * BATCH + j) * stride);
    }
    __builtin_amdgcn_sched_barrier(0);

    // phase 2: B landed -> consume Y, refill Y with D (C still in flight)
    asm volatile("s_waitcnt vmcnt(8)");
    __builtin_amdgcn_sched_barrier(0);
    #pragma unroll
    for (int j = 0; j < BATCH; ++j) acc += hterm4(py[j], pgy[j]);
    #pragma unroll
    for (int j = 0; j < BATCH; ++j) {
        py[j]  = gl4(pred + tid + (3 * BATCH + j) * stride);
        pgy[j] = gl4(gt   + tid + (3 * BATCH + j) * stride);
    }
    __builtin_amdgcn_sched_barrier(0);

    // phase 3: C landed -> consume X (D still in flight)
    asm volatile("s_waitcnt vmcnt(8)");
    __builtin_amdgcn_sched_barrier(0);
    #pragma unroll
    for (int j = 0; j < BATCH; ++j) acc += hterm4(px[j], pgx[j]);
    __builtin_amdgcn_sched_barrier(0);

    // phase 4: drain -> consume Y
    asm volatile("s_waitcnt vmcnt(0)");
    __builtin_amdgcn_sched_barrier(0);
    #pragma unroll
    for (int j = 0; j < BATCH; ++j) acc += hterm4(py[j], pgy[j]);

    #pragma unroll
    for (int off = 32; off > 0; off >>= 1)
        acc += __shfl_down(acc, off, 64);

    __shared__ float wsum[4];
    int lane = threadIdx.x & 63;
    int wave = threadIdx.x >> 6;
    if (lane == 0) wsum[wave] = acc;
    __syncthreads();

    if (threadIdx.x == 0)
        partial[blockIdx.x] = wsum[0] + wsum[1] + wsum[2] + wsum[3];
}

__global__ __launch_bounds__(256) void finalize_kernel(
        const float4* __restrict__ partial4, float* __restrict__ out, int nblocks4) {
    float s = 0.0f;
    for (int i = threadIdx.x; i < nblocks4; i += 256) {
        float4 v = partial4[i];
        s += (v.x + v.y) + (v.z + v.w);
    }

    #pragma unroll
    for (int off = 32; off > 0; off >>= 1)
        s += __shfl_down(s, off, 64);

    __shared__ float wsum[4];
    int lane = threadIdx.x & 63;
    int wave = threadIdx.x >> 6;
    if (lane == 0) wsum[wave] = s;
    __syncthreads();

    if (threadIdx.x == 0)
        out[0] = (wsum[0] + wsum[1] + wsum[2] + wsum[3]) * 0.125f;
}

extern "C" void kernel_launch(void* const* d_in, const int* in_sizes, int n_in,
                              void* d_out, int out_size, void* d_ws, size_t ws_size,
                              hipStream_t stream) {
    const float* pred = (const float*)d_in[0];
    const float* gt   = (const float*)d_in[1];
    float* out     = (float*)d_out;
    float* partial = (float*)d_ws;

    int n  = in_sizes[0];        // 2*8*64*128*128 = 16,777,216
    int n4 = n >> 2;             // 4,194,304 float4s

    const int block  = 256;
    const int grid   = n4 / (block * BATCH * NBATCH);  // 1024: persistent, 4 blk/CU
    const int stride = grid * block;                   // float4 stride between steps

    heatmap_reduce_kernel<<<grid, block, 0, stream>>>(
        (const v4f*)pred, (const v4f*)gt, partial, stride);

    finalize_kernel<<<1, block, 0, stream>>>(
        (const float4*)partial, out, grid / 4);
}